// Round 1
// baseline (252.478 us; speedup 1.0000x reference)
//
#include <hip/hip_runtime.h>

// TreeSoftmax: x [B=4, C=144, H=256, W=256] f32 -> same shape.
// 4-ary tree, node i (1..144) <-> channel i-1. parent(i) = (i-1)/4.
// 36 sibling groups of 4; res[i] = softmax_within_group(x)[i] * res[parent(i)].
//
// One thread handles 2 consecutive pixels (float2). Channel stride = H*W.
// Levels processed in order so parent results are in registers when children
// need them; only 16 (level-2) + 15 (level-3 nodes 21..35) results are kept.

struct f2 { float v[2]; };

__device__ __forceinline__ void grp4(const f2 in[4], const f2 pr, f2 out[4]) {
#pragma unroll
    for (int k = 0; k < 2; ++k) {
        float a = in[0].v[k], b = in[1].v[k], c = in[2].v[k], d = in[3].v[k];
        float m = fmaxf(fmaxf(a, b), fmaxf(c, d));
        float e0 = __expf(a - m);
        float e1 = __expf(b - m);
        float e2 = __expf(c - m);
        float e3 = __expf(d - m);
        float s = e0 + e1 + e2 + e3;
        float f = pr.v[k] / s;   // parent prob folded into the normalization
        out[0].v[k] = e0 * f;
        out[1].v[k] = e1 * f;
        out[2].v[k] = e2 * f;
        out[3].v[k] = e3 * f;
    }
}

__global__ __launch_bounds__(256) void tree_softmax_kernel(
        const float* __restrict__ x, float* __restrict__ y) {
    const int HW = 256 * 256;          // per-channel pixel count
    const int C  = 144;
    const int cs = HW / 2;             // channel stride in f2 units

    int tid = blockIdx.x * 256 + threadIdx.x;   // 0 .. 131071
    int b   = tid >> 15;                        // 32768 f2-groups per batch
    int rem = tid & 32767;
    size_t base = (size_t)b * C * HW + (size_t)rem * 2;   // in floats

    const f2* __restrict__ xp = reinterpret_cast<const f2*>(x + base);
    f2*       __restrict__ yp = reinterpret_cast<f2*>(y + base);

    f2 in[4], o[4];

    // ---- level 1: root's children, channels 0..3, parent prob = 1 ----
    f2 r1[4];
    f2 one; one.v[0] = 1.0f; one.v[1] = 1.0f;
#pragma unroll
    for (int c = 0; c < 4; ++c) in[c] = xp[c * cs];
    grp4(in, one, r1);
#pragma unroll
    for (int c = 0; c < 4; ++c) yp[c * cs] = r1[c];

    // ---- level 2: parents = nodes 1..4 (r1), children channels 4..19 ----
    f2 r2[16];
#pragma unroll
    for (int p = 0; p < 4; ++p) {
#pragma unroll
        for (int c = 0; c < 4; ++c) in[c] = xp[(4 + 4 * p + c) * cs];
        grp4(in, r1[p], o);
#pragma unroll
        for (int c = 0; c < 4; ++c) {
            yp[(4 + 4 * p + c) * cs] = o[c];
            r2[4 * p + c] = o[c];
        }
    }

    // ---- level 3: parents = nodes 5..20 (r2), children channels 20..83 ----
    // keep nodes 21..35 (channels 20..34) as level-4 parents
    f2 keep[15];
#pragma unroll
    for (int p = 0; p < 16; ++p) {
#pragma unroll
        for (int c = 0; c < 4; ++c) in[c] = xp[(20 + 4 * p + c) * cs];
        grp4(in, r2[p], o);
#pragma unroll
        for (int c = 0; c < 4; ++c) {
            int idx = 4 * p + c;            // 0..63, channel 20+idx
            yp[(20 + idx) * cs] = o[c];
            if (idx < 15) keep[idx] = o[c]; // compile-time after unroll
        }
    }

    // ---- level 4: parents = nodes 21..35 (keep), children channels 84..143 ----
#pragma unroll
    for (int p = 0; p < 15; ++p) {
#pragma unroll
        for (int c = 0; c < 4; ++c) in[c] = xp[(84 + 4 * p + c) * cs];
        grp4(in, keep[p], o);
#pragma unroll
        for (int c = 0; c < 4; ++c) yp[(84 + 4 * p + c) * cs] = o[c];
    }
}

extern "C" void kernel_launch(void* const* d_in, const int* in_sizes, int n_in,
                              void* d_out, int out_size, void* d_ws, size_t ws_size,
                              hipStream_t stream) {
    const float* x = (const float*)d_in[0];
    float* y = (float*)d_out;
    // B*H*W / 2 pixels-pairs = 131072 threads
    const int threads = 256;
    const int blocks  = (4 * 256 * 256 / 2) / threads;   // 512
    tree_softmax_kernel<<<blocks, threads, 0, stream>>>(x, y);
}